// Round 18
// baseline (218.486 us; speedup 1.0000x reference)
//
#include <hip/hip_runtime.h>
#include <math.h>

#define LEAKY 0.01f
#define BN_EPS 1e-5f
#define NBLK 480          // partition blocks (lin 1563 + 480 = 2043 <= 2048 co-resident)
#define EBUF 10240        // LDS edge-stage capacity in k_csrdeg (40 KB)

typedef unsigned int uint;
typedef float f32x2 __attribute__((ext_vector_type(2)));
typedef float f32x4 __attribute__((ext_vector_type(4)));
typedef short bf16x8 __attribute__((ext_vector_type(8)));

__device__ __forceinline__ float bflo(uint v) { return __uint_as_float(v << 16); }
__device__ __forceinline__ float bfhi(uint v) { return __uint_as_float(v & 0xffff0000u); }
__device__ __forceinline__ uint packbf(float a, float b) {
    uint ua = __float_as_uint(a), ub = __float_as_uint(b);
    ua += 0x7fffu + ((ua >> 16) & 1u);
    ub += 0x7fffu + ((ub >> 16) & 1u);
    return (ua >> 16) | (ub & 0xffff0000u);
}

// Inline probe: int64 edges have all-zero odd 32-bit words (first 64 checked).
__device__ __forceinline__ int detect_i64(const int* __restrict__ raw) {
    int t = threadIdx.x & 63;
    unsigned long long b = __ballot(raw[2 * t + 1] != 0);
    return b == 0ull;
}

// Exclusive scan of btot[0..NBUK) into bb[0..512); works for blockDim >= 256
// (scan work on lanes t<256, barriers executed by all threads).
__device__ __forceinline__ void build_bbase_wide(const int* __restrict__ btot,
                                                 int NBUK, int* bb, int* sd)
{
    const int t = threadIdx.x;
    int a0 = 0, a1 = 0, s = 0;
    if (t < 256) {
        a0 = (2 * t     < NBUK) ? btot[2 * t]     : 0;
        a1 = (2 * t + 1 < NBUK) ? btot[2 * t + 1] : 0;
        s = a0 + a1;
        sd[t] = s;
    }
    __syncthreads();
    for (int o = 1; o < 256; o <<= 1) {
        int u = (t >= o && t < 256) ? sd[t - o] : 0;
        __syncthreads();
        if (t < 256) sd[t] += u;
        __syncthreads();
    }
    if (t < 256) {
        int ex = sd[t] - s;
        bb[2 * t]     = ex;
        bb[2 * t + 1] = ex + a0;
    }
    __syncthreads();
}

// ---------------------------------------------------------------------------
// Prep: Wlin, Wg -> bf16-pair arrays; zero sumsr (32 replicas). 64 blocks x 256.
__global__ __launch_bounds__(256) void k_prep(const float* __restrict__ Wlin,
                                              const float* __restrict__ Wg,
                                              uint* __restrict__ Wlinb,
                                              uint* __restrict__ Wgb,
                                              float* __restrict__ sumsr)
{
    const int idx = blockIdx.x * 256 + threadIdx.x;
    if (blockIdx.x < 32) sumsr[blockIdx.x * 256 + threadIdx.x] = 0.f;
    if (idx < 8192) {
        Wlinb[idx] = packbf(Wlin[2 * idx], Wlin[2 * idx + 1]);
    } else {
        int j = idx - 8192;
        Wgb[j] = packbf(Wg[2 * j], Wg[2 * j + 1]);
    }
}

// ---------------------------------------------------------------------------
// Fused front: blocks [0,G_lin) = GEMM1 (MFMA, x=fea@Wlin^T+blin -> bf16 xb,
// fused BN stats); blocks [G_lin, G_lin+NBLK) = dst-bucket histogram (bhist).
// A-operand loaded direct global->register (nontemporal; no LDS staging pass).
__global__ __launch_bounds__(256) void k_front(const float* __restrict__ fea,
                                               const uint* __restrict__ Wb,
                                               const float* __restrict__ bias,
                                               uint* __restrict__ xb,
                                               float* __restrict__ sumsr,
                                               const void* __restrict__ edges, int E,
                                               int* __restrict__ histm,
                                               int NBUK, int N, int G_lin)
{
    __shared__ uint smem[4352];       // 17408 B: lin stats/pack | bhist hist
    const int tid = threadIdx.x;

    if ((int)blockIdx.x >= G_lin) {
        // ---- bhist role ----
        const int bid = blockIdx.x - G_lin;
        int* hh = (int*)smem;
        for (int b = tid; b < 512; b += 256) hh[b] = 0;
        const int isI64 = detect_i64((const int*)edges);
        __syncthreads();
        const long long* e64 = (const long long*)edges;
        const int*       e32 = (const int*)edges;
        const int chunk = (E + NBLK - 1) / NBLK;
        const int lo = bid * chunk;
        const int hi = min(lo + chunk, E);
        for (int e = lo + tid; e < hi; e += 256) {
            int dst = isI64 ? (int)e64[(size_t)E + e] : e32[(size_t)E + e];
            atomicAdd(&hh[dst >> 8], 1);
        }
        __syncthreads();
        for (int b = tid; b < NBUK; b += 256)
            histm[(size_t)b * NBLK + bid] = hh[b];
        return;
    }

    // ---- lin role ----
    const int r0   = blockIdx.x * 64;
    const int lane = tid & 63;
    const int w    = tid >> 6;
    const int fr   = lane & 15;
    const int fk   = lane >> 4;
    const int gr_a = r0 + w * 16 + fr;   // this lane's A-fragment row

    // A fragments: direct global (nontemporal) load + bf16 convert in registers.
    bf16x8 a[4];
    #pragma unroll
    for (int kk = 0; kk < 4; ++kk) {
        f32x4 q0 = {0.f, 0.f, 0.f, 0.f}, q1 = {0.f, 0.f, 0.f, 0.f};
        if (gr_a < N) {
            const f32x4* fp = reinterpret_cast<const f32x4*>(
                &fea[(size_t)gr_a * 128 + 32 * kk + 8 * fk]);
            q0 = __builtin_nontemporal_load(fp);
            q1 = __builtin_nontemporal_load(fp + 1);
        }
        uint4 uu = make_uint4(packbf(q0.x, q0.y), packbf(q0.z, q0.w),
                              packbf(q1.x, q1.y), packbf(q1.z, q1.w));
        a[kk] = *reinterpret_cast<bf16x8*>(&uu);
    }

    f32x4 acc[8] = {};
    #pragma unroll
    for (int jt = 0; jt < 8; ++jt) {
        #pragma unroll
        for (int kk = 0; kk < 4; ++kk) {
            bf16x8 b = *reinterpret_cast<const bf16x8*>(
                &Wb[(size_t)(jt * 16 + fr) * 64 + kk * 16 + fk * 4]);
            acc[jt] = __builtin_amdgcn_mfma_f32_16x16x32_bf16(a[kk], b, acc[jt], 0, 0, 0);
        }
    }

    float* sred = (float*)smem;       // [16][128]
    float* qred = sred + 2048;        // [16][128]
    #pragma unroll
    for (int jt = 0; jt < 8; ++jt) {
        float bj = bias[jt * 16 + fr];
        float sl = 0.f, ql = 0.f;
        #pragma unroll
        for (int r = 0; r < 4; ++r) {
            int gr = r0 + w * 16 + fk * 4 + r;
            float val = acc[jt][r] + bj;
            val = (gr < N) ? val : 0.f;
            acc[jt][r] = val;
            sl += val; ql += val * val;
        }
        sred[(w * 4 + fk) * 128 + jt * 16 + fr] = sl;
        qred[(w * 4 + fk) * 128 + jt * 16 + fr] = ql;
    }
    __syncthreads();
    if (tid < 128) {
        float S = 0.f, Q = 0.f;
        #pragma unroll
        for (int g = 0; g < 16; ++g) {
            S += sred[g * 128 + tid];
            Q += qred[g * 128 + tid];
        }
        float* dstp = sumsr + (blockIdx.x & 31) * 256;
        atomicAdd(&dstp[tid], S);
        atomicAdd(&dstp[128 + tid], Q);
    }
    __syncthreads();                  // stats reads done; reuse smem for pack

    // pack bf16 pairs into LDS [64][68] then coalesced uint4 store
    #pragma unroll
    for (int jt = 0; jt < 8; ++jt) {
        #pragma unroll
        for (int r = 0; r < 4; ++r) {
            float val = acc[jt][r];
            float pv  = __shfl_xor(val, 1);
            if ((lane & 1) == 0)
                smem[(w * 16 + fk * 4 + r) * 68 + jt * 8 + (fr >> 1)] = packbf(val, pv);
        }
    }
    __syncthreads();
    #pragma unroll
    for (int it = 0; it < 4; ++it) {
        int idx4 = it * 256 + tid;        // 0..1023
        int row  = idx4 >> 4;
        int c4   = idx4 & 15;
        if (r0 + row < N) {
            uint4 v = *reinterpret_cast<const uint4*>(&smem[row * 68 + c4 * 4]);
            *reinterpret_cast<uint4*>(&xb[(size_t)(r0 + row) * 64 + c4 * 4]) = v;
        }
    }
}

// ---------------------------------------------------------------------------
// Pass A2: per-bucket exclusive scan across blocks; emit bucket totals.
__global__ __launch_bounds__(512) void k_bscan(int* __restrict__ histm,
                                               int* __restrict__ btot)
{
    __shared__ int sd[512];
    const int bkt = blockIdx.x;
    const int t = threadIdx.x;
    int v = (t < NBLK) ? histm[(size_t)bkt * NBLK + t] : 0;
    sd[t] = v;
    __syncthreads();
    for (int o = 1; o < 512; o <<= 1) {
        int u = (t >= o) ? sd[t - o] : 0;
        __syncthreads();
        sd[t] += u;
        __syncthreads();
    }
    if (t < NBLK) histm[(size_t)bkt * NBLK + t] = sd[t] - v;   // exclusive
    if (t == 511) btot[bkt] = sd[511];
}

// Pass B: scatter packed (src | dstlow<<24) into dst-bucketed bins. 512 thr.
// Block 0 also finalizes the BN affine coefficients (sumsr complete by now).
__global__ __launch_bounds__(512) void k_binscatter(const void* __restrict__ edges, int E,
                                                    const int* __restrict__ histm,
                                                    const int* __restrict__ btot,
                                                    uint* __restrict__ bins,
                                                    const float* __restrict__ sumsr,
                                                    const float* __restrict__ gamma,
                                                    const float* __restrict__ beta,
                                                    float invN,
                                                    float* __restrict__ affg,
                                                    int NBUK)
{
    __shared__ int cur[512];
    __shared__ int bb[512];
    __shared__ int sd[256];
    const int isI64 = detect_i64((const int*)edges);

    if (blockIdx.x == 0 && threadIdx.x < 128) {
        const int tid = threadIdx.x;
        float S = 0.f, Q = 0.f;
        #pragma unroll
        for (int rep = 0; rep < 32; ++rep) {
            S += sumsr[rep * 256 + tid];
            Q += sumsr[rep * 256 + 128 + tid];
        }
        float mean = S * invN;
        float var  = Q * invN - mean * mean;
        float coef = gamma[tid] * rsqrtf(var + BN_EPS);
        affg[tid]       = coef;
        affg[128 + tid] = beta[tid] - coef * mean;
    }

    build_bbase_wide(btot, NBUK, bb, sd);
    for (int b = threadIdx.x; b < NBUK; b += 512)
        cur[b] = bb[b] + histm[(size_t)b * NBLK + blockIdx.x];
    __syncthreads();

    const long long* e64 = (const long long*)edges;
    const int*       e32 = (const int*)edges;
    const int chunk = (E + NBLK - 1) / NBLK;
    const int lo = blockIdx.x * chunk;
    const int hi = min(lo + chunk, E);
    for (int e = lo + threadIdx.x; e < hi; e += 512) {
        int src, dst;
        if (isI64) { src = (int)e64[e]; dst = (int)e64[(size_t)E + e]; }
        else       { src = e32[e];      dst = e32[(size_t)E + e]; }
        int pos = atomicAdd(&cur[dst >> 8], 1);
        bins[pos] = (uint)src | ((uint)(dst & 255) << 24);
    }
}

// Pass C (merged deg+dinv+offs+CSR, 16-padded): one block per bucket, 1024 thr.
// Also counting-sorts the bucket's nodes by padded degree (descending) into
// nodeord so k_agg blocks hold waves of near-equal work.
__global__ __launch_bounds__(1024) void k_csrdeg(const uint* __restrict__ bins,
                                                 const int* __restrict__ btot,
                                                 int* __restrict__ pcnt,
                                                 float* __restrict__ dinv,
                                                 int* __restrict__ offs,
                                                 uint* __restrict__ csr,
                                                 uint* __restrict__ nodeord,
                                                 int N, int NBUK)
{
    __shared__ uint ebuf[EBUF];
    __shared__ int bb[512];
    __shared__ int sd[256];
    __shared__ int c[256];
    __shared__ int clso[32];
    const int bkt = blockIdx.x;
    const int t = threadIdx.x;
    build_bbase_wide(btot, NBUK, bb, sd);
    const int lo    = bb[bkt];
    const int total = btot[bkt];
    if (t < 256) c[t] = 0;
    if (t >= 256 && t < 288) clso[t - 256] = 0;   // class histogram
    __syncthreads();

    const bool fits = (total <= EBUF);
    for (int i = t; i < total; i += 1024) {
        uint e = bins[lo + i];
        if (fits) ebuf[i] = e;
        atomicAdd(&c[e >> 24], 1);
    }
    __syncthreads();

    const int node = (bkt << 8) + t;
    int deg = 0, pdeg = 0, cls = 0;
    if (t < 256) {
        deg  = c[t];
        pdeg = (deg + 15) & ~15;                  // pad to multiple of 16
        cls  = min(pdeg >> 4, 31);
        if (node < N) {
            pcnt[node] = pdeg;
            dinv[node] = rsqrtf((float)(deg + 1));
        }
        atomicAdd(&clso[cls], 1);
        sd[t] = pdeg;
    }
    __syncthreads();
    // descending-class offsets (single thread; 32 classes)
    if (t == 0) {
        int run = 0;
        #pragma unroll
        for (int cc = 31; cc >= 0; --cc) { int v = clso[cc]; clso[cc] = run; run += v; }
    }
    __syncthreads();
    if (t < 256) {
        int rank = atomicAdd(&clso[cls], 1);
        nodeord[(bkt << 8) + rank] = (node < N) ? (uint)node : 0xFFFFFFFFu;
    }
    __syncthreads();
    for (int o = 1; o < 256; o <<= 1) {
        int u = (t >= o && t < 256) ? sd[t - o] : 0;
        __syncthreads();
        if (t < 256) sd[t] += u;
        __syncthreads();
    }
    // padded bucket base: unpadded base + bkt*4096 (max pad 256*15 < 4096)
    if (t < 256) {
        const int myoff = lo + (bkt << 12) + sd[t] - pdeg;
        if (node < N) offs[node] = myoff;
        c[t] = myoff;                             // reuse as write cursor
    }
    __syncthreads();
    for (int i = t; i < total; i += 1024) {
        uint e = fits ? ebuf[i] : bins[lo + i];
        int pos = atomicAdd(&c[e >> 24], 1);
        csr[pos] = e & 0x00ffffffu;
    }
    // padding slots -> dummy node N (its hb row is all zeros)
    if (t < 256) {
        const int myoff = lo + (bkt << 12) + sd[t] - pdeg;
        for (int k2 = deg; k2 < pdeg; ++k2)
            csr[myoff + k2] = (uint)N;
    }
}

// ---------------------------------------------------------------------------
// GEMM2 (MFMA): h' = dinv * (leakyrelu(a*x + b) @ Wg^T) -> fp8(e4m3) hb.
// A-operand: direct global load + affine+leaky in registers; aff precomputed.
__global__ __launch_bounds__(256) void k_h(const uint* __restrict__ xb,
                                           const uint* __restrict__ Wb,
                                           const float* __restrict__ affg,
                                           const float* __restrict__ dinv,
                                           uint* __restrict__ hb, int N)
{
    __shared__ uint xls[2304];        // fp8 pack stage [64][36]
    __shared__ float aff[256];
    const int tid  = threadIdx.x;
    const int r0   = blockIdx.x * 64;
    const int lane = tid & 63;
    const int w    = tid >> 6;
    const int fr   = lane & 15;
    const int fk   = lane >> 4;

    aff[tid] = affg[tid & 255];
    __syncthreads();

    const int gr_a = r0 + w * 16 + fr;
    bf16x8 a[4];
    #pragma unroll
    for (int kk = 0; kk < 4; ++kk) {
        uint4 xv = make_uint4(0u, 0u, 0u, 0u);
        if (gr_a < N)
            xv = *reinterpret_cast<const uint4*>(&xb[(size_t)gr_a * 64 + kk * 16 + fk * 4]);
        const int fb = 2 * (kk * 16 + fk * 4);    // first feature index
        uint uv[4] = {xv.x, xv.y, xv.z, xv.w};
        uint ou[4];
        #pragma unroll
        for (int t2 = 0; t2 < 4; ++t2) {
            float y0 = fmaf(aff[fb + 2 * t2],     bflo(uv[t2]), aff[128 + fb + 2 * t2]);
            float y1 = fmaf(aff[fb + 2 * t2 + 1], bfhi(uv[t2]), aff[128 + fb + 2 * t2 + 1]);
            y0 = (y0 >= 0.f) ? y0 : LEAKY * y0;
            y1 = (y1 >= 0.f) ? y1 : LEAKY * y1;
            ou[t2] = packbf(y0, y1);
        }
        uint4 uu = make_uint4(ou[0], ou[1], ou[2], ou[3]);
        a[kk] = *reinterpret_cast<bf16x8*>(&uu);
    }

    f32x4 acc[8] = {};
    #pragma unroll
    for (int jt = 0; jt < 8; ++jt) {
        #pragma unroll
        for (int kk = 0; kk < 4; ++kk) {
            bf16x8 b = *reinterpret_cast<const bf16x8*>(
                &Wb[(size_t)(jt * 16 + fr) * 64 + kk * 16 + fk * 4]);
            acc[jt] = __builtin_amdgcn_mfma_f32_16x16x32_bf16(a[kk], b, acc[jt], 0, 0, 0);
        }
    }

    float dv[4];
    #pragma unroll
    for (int r = 0; r < 4; ++r) {
        int gr = r0 + w * 16 + fk * 4 + r;
        dv[r] = (gr < N) ? dinv[gr] : 0.f;        // row N (and beyond) -> 0
    }

    #pragma unroll
    for (int jt = 0; jt < 8; ++jt) {
        #pragma unroll
        for (int r = 0; r < 4; ++r) {
            float val = acc[jt][r] * dv[r];
            float p1  = __shfl_xor(val, 1);
            uint lo16 = (uint)__builtin_amdgcn_cvt_pk_fp8_f32(val, p1, 0, false) & 0xffffu;
            uint hi16 = __shfl_xor(lo16, 2);
            if ((fr & 3) == 0)
                xls[(w * 16 + fk * 4 + r) * 36 + jt * 4 + (fr >> 2)] = lo16 | (hi16 << 16);
        }
    }
    __syncthreads();
    #pragma unroll
    for (int it = 0; it < 2; ++it) {
        int idx4 = it * 256 + tid;        // 0..511
        int row  = idx4 >> 3;
        int c4   = idx4 & 7;
        if (r0 + row <= N) {              // include zero row N
            uint4 v = *reinterpret_cast<const uint4*>(&xls[row * 36 + c4 * 4]);
            *reinterpret_cast<uint4*>(&hb[(size_t)(r0 + row) * 32 + c4 * 4]) = v;
        }
    }
}

// ---------------------------------------------------------------------------
// Gather aggregation: out[i] = dinv[i]*(sum h'[src] + h'[i]) + bg, log_softmax.
// 1 wave/node via degree-sorted nodeord (uniform wave lengths per block);
// lane = 8B chunk; 4 lane-groups, maskless, 4 loads in flight per 16 edges.
__global__ __launch_bounds__(256) void k_agg(const uint* __restrict__ hb,
                                             const uint* __restrict__ csr,
                                             const int* __restrict__ offs,
                                             const int* __restrict__ pcnt,
                                             const float* __restrict__ dinv,
                                             const float* __restrict__ bg,
                                             const uint* __restrict__ nodeord,
                                             float* __restrict__ out, int NSLOT, int N)
{
    const int slot = (blockIdx.x * blockDim.x + threadIdx.x) >> 6;
    const int lane = threadIdx.x & 63;
    if (slot >= NSLOT) return;
    const uint ni = nodeord[slot];
    if (ni >= (uint)N) return;
    const int i = (int)ni;
    const int p = lane & 15;      // 8-B chunk within row (features 8p..8p+7)
    const int q = lane >> 4;      // edge subgroup 0..3
    const uint2* hbp = reinterpret_cast<const uint2*>(hb) + p;

    f32x2 acc[4] = {};
    const int start = offs[i];
    const int m     = pcnt[i];    // multiple of 16

    __builtin_amdgcn_s_setprio(1);
    for (int base = 0; base < m; base += 64) {
        const int nb = min(64, m - base);          // multiple of 16
        uint sx = (uint)N;
        if (lane < nb)
            sx = __builtin_nontemporal_load(&csr[start + base + lane]);
        for (int j = 0; j < nb; j += 16) {
            int s0 = __shfl((int)sx, j + q);
            int s1 = __shfl((int)sx, j + 4 + q);
            int s2 = __shfl((int)sx, j + 8 + q);
            int s3 = __shfl((int)sx, j + 12 + q);
            const uint2 v0 = hbp[(uint)s0 * 16];
            const uint2 v1 = hbp[(uint)s1 * 16];
            const uint2 v2 = hbp[(uint)s2 * 16];
            const uint2 v3 = hbp[(uint)s3 * 16];
            acc[0] += __builtin_amdgcn_cvt_pk_f32_fp8((int)v0.x, false);
            acc[1] += __builtin_amdgcn_cvt_pk_f32_fp8((int)v0.x, true);
            acc[2] += __builtin_amdgcn_cvt_pk_f32_fp8((int)v0.y, false);
            acc[3] += __builtin_amdgcn_cvt_pk_f32_fp8((int)v0.y, true);
            acc[0] += __builtin_amdgcn_cvt_pk_f32_fp8((int)v1.x, false);
            acc[1] += __builtin_amdgcn_cvt_pk_f32_fp8((int)v1.x, true);
            acc[2] += __builtin_amdgcn_cvt_pk_f32_fp8((int)v1.y, false);
            acc[3] += __builtin_amdgcn_cvt_pk_f32_fp8((int)v1.y, true);
            acc[0] += __builtin_amdgcn_cvt_pk_f32_fp8((int)v2.x, false);
            acc[1] += __builtin_amdgcn_cvt_pk_f32_fp8((int)v2.x, true);
            acc[2] += __builtin_amdgcn_cvt_pk_f32_fp8((int)v2.y, false);
            acc[3] += __builtin_amdgcn_cvt_pk_f32_fp8((int)v2.y, true);
            acc[0] += __builtin_amdgcn_cvt_pk_f32_fp8((int)v3.x, false);
            acc[1] += __builtin_amdgcn_cvt_pk_f32_fp8((int)v3.x, true);
            acc[2] += __builtin_amdgcn_cvt_pk_f32_fp8((int)v3.y, false);
            acc[3] += __builtin_amdgcn_cvt_pk_f32_fp8((int)v3.y, true);
        }
    }
    __builtin_amdgcn_s_setprio(0);

    // reduce the 4 edge subgroups
    #pragma unroll
    for (int r = 0; r < 4; ++r) {
        acc[r].x += __shfl_xor(acc[r].x, 16);
        acc[r].y += __shfl_xor(acc[r].y, 16);
        acc[r].x += __shfl_xor(acc[r].x, 32);
        acc[r].y += __shfl_xor(acc[r].y, 32);
    }

    // self term (h'[i]), then scale by dinv[i], add bias
    const uint2 sv = hbp[(uint)i * 16];
    acc[0] += __builtin_amdgcn_cvt_pk_f32_fp8((int)sv.x, false);
    acc[1] += __builtin_amdgcn_cvt_pk_f32_fp8((int)sv.x, true);
    acc[2] += __builtin_amdgcn_cvt_pk_f32_fp8((int)sv.y, false);
    acc[3] += __builtin_amdgcn_cvt_pk_f32_fp8((int)sv.y, true);

    const float d0 = dinv[i];
    float4 b0 = *reinterpret_cast<const float4*>(&bg[p * 8]);
    float4 b1 = *reinterpret_cast<const float4*>(&bg[p * 8 + 4]);
    float v0 = fmaf(d0, acc[0].x, b0.x);
    float v1 = fmaf(d0, acc[0].y, b0.y);
    float v2 = fmaf(d0, acc[1].x, b0.z);
    float v3 = fmaf(d0, acc[1].y, b0.w);
    float v4 = fmaf(d0, acc[2].x, b1.x);
    float v5 = fmaf(d0, acc[2].y, b1.y);
    float v6 = fmaf(d0, acc[3].x, b1.z);
    float v7 = fmaf(d0, acc[3].y, b1.w);

    // log_softmax over 128 features (distributed across 16 lanes)
    float mx = fmaxf(fmaxf(fmaxf(v0, v1), fmaxf(v2, v3)),
                     fmaxf(fmaxf(v4, v5), fmaxf(v6, v7)));
    #pragma unroll
    for (int o = 8; o > 0; o >>= 1) mx = fmaxf(mx, __shfl_xor(mx, o));
    float sum = __expf(v0 - mx) + __expf(v1 - mx) + __expf(v2 - mx) + __expf(v3 - mx)
              + __expf(v4 - mx) + __expf(v5 - mx) + __expf(v6 - mx) + __expf(v7 - mx);
    #pragma unroll
    for (int o = 8; o > 0; o >>= 1) sum += __shfl_xor(sum, o);
    float ls = mx + __logf(sum);

    if (q == 0) {
        f32x4 o0 = {v0 - ls, v1 - ls, v2 - ls, v3 - ls};
        f32x4 o1 = {v4 - ls, v5 - ls, v6 - ls, v7 - ls};
        __builtin_nontemporal_store(o0, reinterpret_cast<f32x4*>(&out[(size_t)i * 128 + p * 8]));
        __builtin_nontemporal_store(o1, reinterpret_cast<f32x4*>(&out[(size_t)i * 128 + p * 8 + 4]));
    }
}

// ---------------------------------------------------------------------------
extern "C" void kernel_launch(void* const* d_in, const int* in_sizes, int n_in,
                              void* d_out, int out_size, void* d_ws, size_t ws_size,
                              hipStream_t stream)
{
    (void)n_in; (void)out_size; (void)ws_size;
    const float* fea   = (const float*)d_in[0];
    const void*  edges = d_in[1];
    const float* Wlin  = (const float*)d_in[2];
    const float* blin  = (const float*)d_in[3];
    const float* gamma = (const float*)d_in[4];
    const float* beta  = (const float*)d_in[5];
    const float* Wg    = (const float*)d_in[6];
    const float* bg    = (const float*)d_in[7];
    float* out = (float*)d_out;

    const int N    = in_sizes[0] / 128;
    const int E    = in_sizes[1] / 2;
    const int NBUK = (N + 255) >> 8;          // dst buckets (256 nodes each)
    const int GLIN = (N + 63) / 64;
    const int NSLOT = NBUK << 8;
    const float invN = 1.0f / (float)N;

    char* p = (char*)d_ws;
    uint*  xb   = (uint*)p;    p += (size_t)N * 64 * 4;
    uint*  bins = (uint*)p;    p += (size_t)E * 4;
    uint*  hb   = (uint*)p;    p += ((size_t)N + 1) * 32 * 4;  // fp8 h' + zero row
    uint*  csr  = (uint*)p;    p += ((size_t)E + ((size_t)NBUK << 12)) * 4;
    int*   histm = (int*)p;    p += (size_t)NBUK * NBLK * 4;
    float* sumsr = (float*)p;  p += 32 * 256 * 4;              // 32 replicas
    int*   pcnt = (int*)p;     p += (size_t)N * 4;
    int*   offs = (int*)p;     p += (size_t)N * 4;
    float* dinv = (float*)p;   p += (size_t)N * 4;
    int*   btot = (int*)p;     p += 512 * 4;
    float* affg = (float*)p;   p += 256 * 4;
    uint*  nodeord = (uint*)p; p += (size_t)NSLOT * 4;
    uint*  Wlinb = (uint*)p;   p += 8192 * 4;
    uint*  Wgb   = (uint*)p;   p += 8192 * 4;

    // --- prep (W -> bf16, zero sumsr) ---
    k_prep<<<64, 256, 0, stream>>>(Wlin, Wg, Wlinb, Wgb, sumsr);

    // --- fused GEMM1 || edge histogram (2043 blocks <= 2048 co-resident) ---
    k_front<<<GLIN + NBLK, 256, 0, stream>>>(fea, Wlinb, blin, xb, sumsr,
                                             edges, E, histm, NBUK, N, GLIN);

    // --- graph build (binscatter also finalizes BN affine) ---
    k_bscan<<<NBUK, 512, 0, stream>>>(histm, btot);
    k_binscatter<<<NBLK, 512, 0, stream>>>(edges, E, histm, btot, bins,
                                           sumsr, gamma, beta, invN, affg, NBUK);
    k_csrdeg<<<NBUK, 1024, 0, stream>>>(bins, btot, pcnt, dinv, offs, csr,
                                        nodeord, N, NBUK);

    // --- GEMM2 (covers zero row N) ---
    k_h<<<(N + 64) / 64, 256, 0, stream>>>(xb, Wgb, affg, dinv, hb, N);

    // --- aggregation + log_softmax ---
    k_agg<<<(NSLOT + 3) / 4, 256, 0, stream>>>(hb, csr, offs, pcnt, dinv, bg,
                                               nodeord, out, NSLOT, N);
}

// Round 19
// 209.029 us; speedup vs baseline: 1.0452x; 1.0452x over previous
//
#include <hip/hip_runtime.h>
#include <math.h>

#define LEAKY 0.01f
#define BN_EPS 1e-5f
#define NBLK 480          // partition blocks (lin 1563 + 480 = 2043 <= 2048 co-resident)
#define EBUF 10240        // LDS edge-stage capacity in k_csrdeg (40 KB)

typedef unsigned int uint;
typedef float f32x2 __attribute__((ext_vector_type(2)));
typedef float f32x4 __attribute__((ext_vector_type(4)));
typedef short bf16x8 __attribute__((ext_vector_type(8)));

__device__ __forceinline__ float bflo(uint v) { return __uint_as_float(v << 16); }
__device__ __forceinline__ float bfhi(uint v) { return __uint_as_float(v & 0xffff0000u); }
__device__ __forceinline__ uint packbf(float a, float b) {
    uint ua = __float_as_uint(a), ub = __float_as_uint(b);
    ua += 0x7fffu + ((ua >> 16) & 1u);
    ub += 0x7fffu + ((ub >> 16) & 1u);
    return (ua >> 16) | (ub & 0xffff0000u);
}

// Inline probe: int64 edges have all-zero odd 32-bit words (first 64 checked).
__device__ __forceinline__ int detect_i64(const int* __restrict__ raw) {
    int t = threadIdx.x & 63;
    unsigned long long b = __ballot(raw[2 * t + 1] != 0);
    return b == 0ull;
}

// Exclusive scan of btot[0..NBUK) into bb[0..512); works for blockDim >= 256
// (scan work on lanes t<256, barriers executed by all threads).
__device__ __forceinline__ void build_bbase_wide(const int* __restrict__ btot,
                                                 int NBUK, int* bb, int* sd)
{
    const int t = threadIdx.x;
    int a0 = 0, a1 = 0, s = 0;
    if (t < 256) {
        a0 = (2 * t     < NBUK) ? btot[2 * t]     : 0;
        a1 = (2 * t + 1 < NBUK) ? btot[2 * t + 1] : 0;
        s = a0 + a1;
        sd[t] = s;
    }
    __syncthreads();
    for (int o = 1; o < 256; o <<= 1) {
        int u = (t >= o && t < 256) ? sd[t - o] : 0;
        __syncthreads();
        if (t < 256) sd[t] += u;
        __syncthreads();
    }
    if (t < 256) {
        int ex = sd[t] - s;
        bb[2 * t]     = ex;
        bb[2 * t + 1] = ex + a0;
    }
    __syncthreads();
}

// ---------------------------------------------------------------------------
// Prep: Wlin, Wg -> bf16-pair arrays; zero sumsr (32 replicas). 64 blocks x 256.
__global__ __launch_bounds__(256) void k_prep(const float* __restrict__ Wlin,
                                              const float* __restrict__ Wg,
                                              uint* __restrict__ Wlinb,
                                              uint* __restrict__ Wgb,
                                              float* __restrict__ sumsr)
{
    const int idx = blockIdx.x * 256 + threadIdx.x;
    if (blockIdx.x < 32) sumsr[blockIdx.x * 256 + threadIdx.x] = 0.f;
    if (idx < 8192) {
        Wlinb[idx] = packbf(Wlin[2 * idx], Wlin[2 * idx + 1]);
    } else {
        int j = idx - 8192;
        Wgb[j] = packbf(Wg[2 * j], Wg[2 * j + 1]);
    }
}

// ---------------------------------------------------------------------------
// Fused front: blocks [0,G_lin) = GEMM1 (MFMA, x=fea@Wlin^T+blin -> bf16 xb,
// fused BN stats); blocks [G_lin, G_lin+NBLK) = dst-bucket histogram (bhist).
// A-operand loaded direct global->register (no LDS staging pass).
__global__ __launch_bounds__(256) void k_front(const float* __restrict__ fea,
                                               const uint* __restrict__ Wb,
                                               const float* __restrict__ bias,
                                               uint* __restrict__ xb,
                                               float* __restrict__ sumsr,
                                               const void* __restrict__ edges, int E,
                                               int* __restrict__ histm,
                                               int NBUK, int N, int G_lin)
{
    __shared__ uint smem[4352];       // 17408 B: lin stats/pack | bhist hist
    const int tid = threadIdx.x;

    if ((int)blockIdx.x >= G_lin) {
        // ---- bhist role ----
        const int bid = blockIdx.x - G_lin;
        int* hh = (int*)smem;
        for (int b = tid; b < 512; b += 256) hh[b] = 0;
        const int isI64 = detect_i64((const int*)edges);
        __syncthreads();
        const long long* e64 = (const long long*)edges;
        const int*       e32 = (const int*)edges;
        const int chunk = (E + NBLK - 1) / NBLK;
        const int lo = bid * chunk;
        const int hi = min(lo + chunk, E);
        for (int e = lo + tid; e < hi; e += 256) {
            int dst = isI64 ? (int)e64[(size_t)E + e] : e32[(size_t)E + e];
            atomicAdd(&hh[dst >> 8], 1);
        }
        __syncthreads();
        for (int b = tid; b < NBUK; b += 256)
            histm[(size_t)b * NBLK + bid] = hh[b];
        return;
    }

    // ---- lin role ----
    const int r0   = blockIdx.x * 64;
    const int lane = tid & 63;
    const int w    = tid >> 6;
    const int fr   = lane & 15;
    const int fk   = lane >> 4;
    const int gr_a = r0 + w * 16 + fr;   // this lane's A-fragment row

    // A fragments: direct global load + bf16 convert in registers.
    bf16x8 a[4];
    #pragma unroll
    for (int kk = 0; kk < 4; ++kk) {
        float4 q0 = make_float4(0.f, 0.f, 0.f, 0.f), q1 = q0;
        if (gr_a < N) {
            const float* fp = &fea[(size_t)gr_a * 128 + 32 * kk + 8 * fk];
            q0 = *reinterpret_cast<const float4*>(fp);
            q1 = *reinterpret_cast<const float4*>(fp + 4);
        }
        uint4 uu = make_uint4(packbf(q0.x, q0.y), packbf(q0.z, q0.w),
                              packbf(q1.x, q1.y), packbf(q1.z, q1.w));
        a[kk] = *reinterpret_cast<bf16x8*>(&uu);
    }

    f32x4 acc[8] = {};
    #pragma unroll
    for (int jt = 0; jt < 8; ++jt) {
        #pragma unroll
        for (int kk = 0; kk < 4; ++kk) {
            bf16x8 b = *reinterpret_cast<const bf16x8*>(
                &Wb[(size_t)(jt * 16 + fr) * 64 + kk * 16 + fk * 4]);
            acc[jt] = __builtin_amdgcn_mfma_f32_16x16x32_bf16(a[kk], b, acc[jt], 0, 0, 0);
        }
    }

    float* sred = (float*)smem;       // [16][128]
    float* qred = sred + 2048;        // [16][128]
    #pragma unroll
    for (int jt = 0; jt < 8; ++jt) {
        float bj = bias[jt * 16 + fr];
        float sl = 0.f, ql = 0.f;
        #pragma unroll
        for (int r = 0; r < 4; ++r) {
            int gr = r0 + w * 16 + fk * 4 + r;
            float val = acc[jt][r] + bj;
            val = (gr < N) ? val : 0.f;
            acc[jt][r] = val;
            sl += val; ql += val * val;
        }
        sred[(w * 4 + fk) * 128 + jt * 16 + fr] = sl;
        qred[(w * 4 + fk) * 128 + jt * 16 + fr] = ql;
    }
    __syncthreads();
    if (tid < 128) {
        float S = 0.f, Q = 0.f;
        #pragma unroll
        for (int g = 0; g < 16; ++g) {
            S += sred[g * 128 + tid];
            Q += qred[g * 128 + tid];
        }
        float* dstp = sumsr + (blockIdx.x & 31) * 256;
        atomicAdd(&dstp[tid], S);
        atomicAdd(&dstp[128 + tid], Q);
    }
    __syncthreads();                  // stats reads done; reuse smem for pack

    // pack bf16 pairs into LDS [64][68] then coalesced uint4 store
    #pragma unroll
    for (int jt = 0; jt < 8; ++jt) {
        #pragma unroll
        for (int r = 0; r < 4; ++r) {
            float val = acc[jt][r];
            float pv  = __shfl_xor(val, 1);
            if ((lane & 1) == 0)
                smem[(w * 16 + fk * 4 + r) * 68 + jt * 8 + (fr >> 1)] = packbf(val, pv);
        }
    }
    __syncthreads();
    #pragma unroll
    for (int it = 0; it < 4; ++it) {
        int idx4 = it * 256 + tid;        // 0..1023
        int row  = idx4 >> 4;
        int c4   = idx4 & 15;
        if (r0 + row < N) {
            uint4 v = *reinterpret_cast<const uint4*>(&smem[row * 68 + c4 * 4]);
            *reinterpret_cast<uint4*>(&xb[(size_t)(r0 + row) * 64 + c4 * 4]) = v;
        }
    }
}

// ---------------------------------------------------------------------------
// Pass A2: per-bucket exclusive scan across blocks; emit bucket totals.
__global__ __launch_bounds__(512) void k_bscan(int* __restrict__ histm,
                                               int* __restrict__ btot)
{
    __shared__ int sd[512];
    const int bkt = blockIdx.x;
    const int t = threadIdx.x;
    int v = (t < NBLK) ? histm[(size_t)bkt * NBLK + t] : 0;
    sd[t] = v;
    __syncthreads();
    for (int o = 1; o < 512; o <<= 1) {
        int u = (t >= o) ? sd[t - o] : 0;
        __syncthreads();
        sd[t] += u;
        __syncthreads();
    }
    if (t < NBLK) histm[(size_t)bkt * NBLK + t] = sd[t] - v;   // exclusive
    if (t == 511) btot[bkt] = sd[511];
}

// Pass B: scatter packed (src | dstlow<<24) into dst-bucketed bins. 512 thr.
// Block 0 also finalizes the BN affine coefficients (sumsr complete by now).
__global__ __launch_bounds__(512) void k_binscatter(const void* __restrict__ edges, int E,
                                                    const int* __restrict__ histm,
                                                    const int* __restrict__ btot,
                                                    uint* __restrict__ bins,
                                                    const float* __restrict__ sumsr,
                                                    const float* __restrict__ gamma,
                                                    const float* __restrict__ beta,
                                                    float invN,
                                                    float* __restrict__ affg,
                                                    int NBUK)
{
    __shared__ int cur[512];
    __shared__ int bb[512];
    __shared__ int sd[256];
    const int isI64 = detect_i64((const int*)edges);

    if (blockIdx.x == 0 && threadIdx.x < 128) {
        const int tid = threadIdx.x;
        float S = 0.f, Q = 0.f;
        #pragma unroll
        for (int rep = 0; rep < 32; ++rep) {
            S += sumsr[rep * 256 + tid];
            Q += sumsr[rep * 256 + 128 + tid];
        }
        float mean = S * invN;
        float var  = Q * invN - mean * mean;
        float coef = gamma[tid] * rsqrtf(var + BN_EPS);
        affg[tid]       = coef;
        affg[128 + tid] = beta[tid] - coef * mean;
    }

    build_bbase_wide(btot, NBUK, bb, sd);
    for (int b = threadIdx.x; b < NBUK; b += 512)
        cur[b] = bb[b] + histm[(size_t)b * NBLK + blockIdx.x];
    __syncthreads();

    const long long* e64 = (const long long*)edges;
    const int*       e32 = (const int*)edges;
    const int chunk = (E + NBLK - 1) / NBLK;
    const int lo = blockIdx.x * chunk;
    const int hi = min(lo + chunk, E);
    for (int e = lo + threadIdx.x; e < hi; e += 512) {
        int src, dst;
        if (isI64) { src = (int)e64[e]; dst = (int)e64[(size_t)E + e]; }
        else       { src = e32[e];      dst = e32[(size_t)E + e]; }
        int pos = atomicAdd(&cur[dst >> 8], 1);
        bins[pos] = (uint)src | ((uint)(dst & 255) << 24);
    }
}

// Pass C (merged deg+dinv+offs+CSR, 16-padded): one block per bucket, 1024 thr.
// Each node's csr list is padded to a multiple of 16 with dummy id N (zero row).
__global__ __launch_bounds__(1024) void k_csrdeg(const uint* __restrict__ bins,
                                                 const int* __restrict__ btot,
                                                 int* __restrict__ pcnt,
                                                 float* __restrict__ dinv,
                                                 int* __restrict__ offs,
                                                 uint* __restrict__ csr,
                                                 int N, int NBUK)
{
    __shared__ uint ebuf[EBUF];
    __shared__ int bb[512];
    __shared__ int sd[256];
    __shared__ int c[256];
    const int bkt = blockIdx.x;
    const int t = threadIdx.x;
    build_bbase_wide(btot, NBUK, bb, sd);
    const int lo    = bb[bkt];
    const int total = btot[bkt];
    if (t < 256) c[t] = 0;
    __syncthreads();

    const bool fits = (total <= EBUF);
    for (int i = t; i < total; i += 1024) {
        uint e = bins[lo + i];
        if (fits) ebuf[i] = e;
        atomicAdd(&c[e >> 24], 1);
    }
    __syncthreads();

    const int node = (bkt << 8) + t;
    int deg = 0, pdeg = 0;
    if (t < 256) {
        deg  = c[t];
        pdeg = (deg + 15) & ~15;                  // pad to multiple of 16
        if (node < N) {
            pcnt[node] = pdeg;
            dinv[node] = rsqrtf((float)(deg + 1));
        }
        sd[t] = pdeg;
    }
    __syncthreads();
    for (int o = 1; o < 256; o <<= 1) {
        int u = (t >= o && t < 256) ? sd[t - o] : 0;
        __syncthreads();
        if (t < 256) sd[t] += u;
        __syncthreads();
    }
    // padded bucket base: unpadded base + bkt*4096 (max pad 256*15 < 4096)
    if (t < 256) {
        const int myoff = lo + (bkt << 12) + sd[t] - pdeg;
        if (node < N) offs[node] = myoff;
        c[t] = myoff;                             // reuse as write cursor
    }
    __syncthreads();
    for (int i = t; i < total; i += 1024) {
        uint e = fits ? ebuf[i] : bins[lo + i];
        int pos = atomicAdd(&c[e >> 24], 1);
        csr[pos] = e & 0x00ffffffu;
    }
    // padding slots -> dummy node N (its hb row is all zeros)
    if (t < 256) {
        const int myoff = lo + (bkt << 12) + sd[t] - pdeg;
        for (int k2 = deg; k2 < pdeg; ++k2)
            csr[myoff + k2] = (uint)N;
    }
}

// ---------------------------------------------------------------------------
// GEMM2 (MFMA): h' = dinv * (leakyrelu(a*x + b) @ Wg^T) -> fp8(e4m3) hb.
// A-operand: direct global load + affine+leaky in registers; aff precomputed.
__global__ __launch_bounds__(256) void k_h(const uint* __restrict__ xb,
                                           const uint* __restrict__ Wb,
                                           const float* __restrict__ affg,
                                           const float* __restrict__ dinv,
                                           uint* __restrict__ hb, int N)
{
    __shared__ uint xls[2304];        // fp8 pack stage [64][36]
    __shared__ float aff[256];
    const int tid  = threadIdx.x;
    const int r0   = blockIdx.x * 64;
    const int lane = tid & 63;
    const int w    = tid >> 6;
    const int fr   = lane & 15;
    const int fk   = lane >> 4;

    aff[tid] = affg[tid & 255];
    __syncthreads();

    const int gr_a = r0 + w * 16 + fr;
    bf16x8 a[4];
    #pragma unroll
    for (int kk = 0; kk < 4; ++kk) {
        uint4 xv = make_uint4(0u, 0u, 0u, 0u);
        if (gr_a < N)
            xv = *reinterpret_cast<const uint4*>(&xb[(size_t)gr_a * 64 + kk * 16 + fk * 4]);
        const int fb = 2 * (kk * 16 + fk * 4);    // first feature index
        uint uv[4] = {xv.x, xv.y, xv.z, xv.w};
        uint ou[4];
        #pragma unroll
        for (int t2 = 0; t2 < 4; ++t2) {
            float y0 = fmaf(aff[fb + 2 * t2],     bflo(uv[t2]), aff[128 + fb + 2 * t2]);
            float y1 = fmaf(aff[fb + 2 * t2 + 1], bfhi(uv[t2]), aff[128 + fb + 2 * t2 + 1]);
            y0 = (y0 >= 0.f) ? y0 : LEAKY * y0;
            y1 = (y1 >= 0.f) ? y1 : LEAKY * y1;
            ou[t2] = packbf(y0, y1);
        }
        uint4 uu = make_uint4(ou[0], ou[1], ou[2], ou[3]);
        a[kk] = *reinterpret_cast<bf16x8*>(&uu);
    }

    f32x4 acc[8] = {};
    #pragma unroll
    for (int jt = 0; jt < 8; ++jt) {
        #pragma unroll
        for (int kk = 0; kk < 4; ++kk) {
            bf16x8 b = *reinterpret_cast<const bf16x8*>(
                &Wb[(size_t)(jt * 16 + fr) * 64 + kk * 16 + fk * 4]);
            acc[jt] = __builtin_amdgcn_mfma_f32_16x16x32_bf16(a[kk], b, acc[jt], 0, 0, 0);
        }
    }

    float dv[4];
    #pragma unroll
    for (int r = 0; r < 4; ++r) {
        int gr = r0 + w * 16 + fk * 4 + r;
        dv[r] = (gr < N) ? dinv[gr] : 0.f;        // row N (and beyond) -> 0
    }

    #pragma unroll
    for (int jt = 0; jt < 8; ++jt) {
        #pragma unroll
        for (int r = 0; r < 4; ++r) {
            float val = acc[jt][r] * dv[r];
            float p1  = __shfl_xor(val, 1);
            uint lo16 = (uint)__builtin_amdgcn_cvt_pk_fp8_f32(val, p1, 0, false) & 0xffffu;
            uint hi16 = __shfl_xor(lo16, 2);
            if ((fr & 3) == 0)
                xls[(w * 16 + fk * 4 + r) * 36 + jt * 4 + (fr >> 2)] = lo16 | (hi16 << 16);
        }
    }
    __syncthreads();
    #pragma unroll
    for (int it = 0; it < 2; ++it) {
        int idx4 = it * 256 + tid;        // 0..511
        int row  = idx4 >> 3;
        int c4   = idx4 & 7;
        if (r0 + row <= N) {              // include zero row N
            uint4 v = *reinterpret_cast<const uint4*>(&xls[row * 36 + c4 * 4]);
            *reinterpret_cast<uint4*>(&hb[(size_t)(r0 + row) * 32 + c4 * 4]) = v;
        }
    }
}

// ---------------------------------------------------------------------------
// Gather aggregation: out[i] = dinv[i]*(sum h'[src] + h'[i]) + bg, log_softmax.
// 1 wave/node; lane = 8B chunk (8 fp8 features); 4 lane-groups, maskless,
// 4 independent loads in flight per 16-edge group (lists padded to x16).
__global__ __launch_bounds__(256) void k_agg(const uint* __restrict__ hb,
                                             const uint* __restrict__ csr,
                                             const int* __restrict__ offs,
                                             const int* __restrict__ pcnt,
                                             const float* __restrict__ dinv,
                                             const float* __restrict__ bg,
                                             float* __restrict__ out, int N)
{
    const int wid  = (blockIdx.x * blockDim.x + threadIdx.x) >> 6;
    const int lane = threadIdx.x & 63;
    if (wid >= N) return;
    const int i = wid;
    const int p = lane & 15;      // 8-B chunk within row (features 8p..8p+7)
    const int q = lane >> 4;      // edge subgroup 0..3
    const uint2* hbp = reinterpret_cast<const uint2*>(hb) + p;

    f32x2 acc[4] = {};
    const int start = offs[i];
    const int m     = pcnt[i];    // multiple of 16

    for (int base = 0; base < m; base += 64) {
        const int nb = min(64, m - base);          // multiple of 16
        uint sx = (uint)N;
        if (lane < nb)
            sx = __builtin_nontemporal_load(&csr[start + base + lane]);
        for (int j = 0; j < nb; j += 16) {
            int s0 = __shfl((int)sx, j + q);
            int s1 = __shfl((int)sx, j + 4 + q);
            int s2 = __shfl((int)sx, j + 8 + q);
            int s3 = __shfl((int)sx, j + 12 + q);
            const uint2 v0 = hbp[(uint)s0 * 16];
            const uint2 v1 = hbp[(uint)s1 * 16];
            const uint2 v2 = hbp[(uint)s2 * 16];
            const uint2 v3 = hbp[(uint)s3 * 16];
            acc[0] += __builtin_amdgcn_cvt_pk_f32_fp8((int)v0.x, false);
            acc[1] += __builtin_amdgcn_cvt_pk_f32_fp8((int)v0.x, true);
            acc[2] += __builtin_amdgcn_cvt_pk_f32_fp8((int)v0.y, false);
            acc[3] += __builtin_amdgcn_cvt_pk_f32_fp8((int)v0.y, true);
            acc[0] += __builtin_amdgcn_cvt_pk_f32_fp8((int)v1.x, false);
            acc[1] += __builtin_amdgcn_cvt_pk_f32_fp8((int)v1.x, true);
            acc[2] += __builtin_amdgcn_cvt_pk_f32_fp8((int)v1.y, false);
            acc[3] += __builtin_amdgcn_cvt_pk_f32_fp8((int)v1.y, true);
            acc[0] += __builtin_amdgcn_cvt_pk_f32_fp8((int)v2.x, false);
            acc[1] += __builtin_amdgcn_cvt_pk_f32_fp8((int)v2.x, true);
            acc[2] += __builtin_amdgcn_cvt_pk_f32_fp8((int)v2.y, false);
            acc[3] += __builtin_amdgcn_cvt_pk_f32_fp8((int)v2.y, true);
            acc[0] += __builtin_amdgcn_cvt_pk_f32_fp8((int)v3.x, false);
            acc[1] += __builtin_amdgcn_cvt_pk_f32_fp8((int)v3.x, true);
            acc[2] += __builtin_amdgcn_cvt_pk_f32_fp8((int)v3.y, false);
            acc[3] += __builtin_amdgcn_cvt_pk_f32_fp8((int)v3.y, true);
        }
    }

    // reduce the 4 edge subgroups
    #pragma unroll
    for (int r = 0; r < 4; ++r) {
        acc[r].x += __shfl_xor(acc[r].x, 16);
        acc[r].y += __shfl_xor(acc[r].y, 16);
        acc[r].x += __shfl_xor(acc[r].x, 32);
        acc[r].y += __shfl_xor(acc[r].y, 32);
    }

    // self term (h'[i]), then scale by dinv[i], add bias
    const uint2 sv = hbp[(uint)i * 16];
    acc[0] += __builtin_amdgcn_cvt_pk_f32_fp8((int)sv.x, false);
    acc[1] += __builtin_amdgcn_cvt_pk_f32_fp8((int)sv.x, true);
    acc[2] += __builtin_amdgcn_cvt_pk_f32_fp8((int)sv.y, false);
    acc[3] += __builtin_amdgcn_cvt_pk_f32_fp8((int)sv.y, true);

    const float d0 = dinv[i];
    float4 b0 = *reinterpret_cast<const float4*>(&bg[p * 8]);
    float4 b1 = *reinterpret_cast<const float4*>(&bg[p * 8 + 4]);
    float v0 = fmaf(d0, acc[0].x, b0.x);
    float v1 = fmaf(d0, acc[0].y, b0.y);
    float v2 = fmaf(d0, acc[1].x, b0.z);
    float v3 = fmaf(d0, acc[1].y, b0.w);
    float v4 = fmaf(d0, acc[2].x, b1.x);
    float v5 = fmaf(d0, acc[2].y, b1.y);
    float v6 = fmaf(d0, acc[3].x, b1.z);
    float v7 = fmaf(d0, acc[3].y, b1.w);

    // log_softmax over 128 features (distributed across 16 lanes)
    float mx = fmaxf(fmaxf(fmaxf(v0, v1), fmaxf(v2, v3)),
                     fmaxf(fmaxf(v4, v5), fmaxf(v6, v7)));
    #pragma unroll
    for (int o = 8; o > 0; o >>= 1) mx = fmaxf(mx, __shfl_xor(mx, o));
    float sum = __expf(v0 - mx) + __expf(v1 - mx) + __expf(v2 - mx) + __expf(v3 - mx)
              + __expf(v4 - mx) + __expf(v5 - mx) + __expf(v6 - mx) + __expf(v7 - mx);
    #pragma unroll
    for (int o = 8; o > 0; o >>= 1) sum += __shfl_xor(sum, o);
    float ls = mx + __logf(sum);

    if (q == 0) {
        f32x4 o0 = {v0 - ls, v1 - ls, v2 - ls, v3 - ls};
        f32x4 o1 = {v4 - ls, v5 - ls, v6 - ls, v7 - ls};
        __builtin_nontemporal_store(o0, reinterpret_cast<f32x4*>(&out[(size_t)i * 128 + p * 8]));
        __builtin_nontemporal_store(o1, reinterpret_cast<f32x4*>(&out[(size_t)i * 128 + p * 8 + 4]));
    }
}

// ---------------------------------------------------------------------------
extern "C" void kernel_launch(void* const* d_in, const int* in_sizes, int n_in,
                              void* d_out, int out_size, void* d_ws, size_t ws_size,
                              hipStream_t stream)
{
    (void)n_in; (void)out_size; (void)ws_size;
    const float* fea   = (const float*)d_in[0];
    const void*  edges = d_in[1];
    const float* Wlin  = (const float*)d_in[2];
    const float* blin  = (const float*)d_in[3];
    const float* gamma = (const float*)d_in[4];
    const float* beta  = (const float*)d_in[5];
    const float* Wg    = (const float*)d_in[6];
    const float* bg    = (const float*)d_in[7];
    float* out = (float*)d_out;

    const int N    = in_sizes[0] / 128;
    const int E    = in_sizes[1] / 2;
    const int NBUK = (N + 255) >> 8;          // dst buckets (256 nodes each)
    const int GLIN = (N + 63) / 64;
    const float invN = 1.0f / (float)N;

    char* p = (char*)d_ws;
    uint*  xb   = (uint*)p;    p += (size_t)N * 64 * 4;
    uint*  bins = (uint*)p;    p += (size_t)E * 4;
    uint*  hb   = (uint*)p;    p += ((size_t)N + 1) * 32 * 4;  // fp8 h' + zero row
    uint*  csr  = (uint*)p;    p += ((size_t)E + ((size_t)NBUK << 12)) * 4;
    int*   histm = (int*)p;    p += (size_t)NBUK * NBLK * 4;
    float* sumsr = (float*)p;  p += 32 * 256 * 4;              // 32 replicas
    int*   pcnt = (int*)p;     p += (size_t)N * 4;
    int*   offs = (int*)p;     p += (size_t)N * 4;
    float* dinv = (float*)p;   p += (size_t)N * 4;
    int*   btot = (int*)p;     p += 512 * 4;
    float* affg = (float*)p;   p += 256 * 4;
    uint*  Wlinb = (uint*)p;   p += 8192 * 4;
    uint*  Wgb   = (uint*)p;   p += 8192 * 4;

    // --- prep (W -> bf16, zero sumsr) ---
    k_prep<<<64, 256, 0, stream>>>(Wlin, Wg, Wlinb, Wgb, sumsr);

    // --- fused GEMM1 || edge histogram (2043 blocks <= 2048 co-resident) ---
    k_front<<<GLIN + NBLK, 256, 0, stream>>>(fea, Wlinb, blin, xb, sumsr,
                                             edges, E, histm, NBUK, N, GLIN);

    // --- graph build (binscatter also finalizes BN affine) ---
    k_bscan<<<NBUK, 512, 0, stream>>>(histm, btot);
    k_binscatter<<<NBLK, 512, 0, stream>>>(edges, E, histm, btot, bins,
                                           sumsr, gamma, beta, invN, affg, NBUK);
    k_csrdeg<<<NBUK, 1024, 0, stream>>>(bins, btot, pcnt, dinv, offs, csr, N, NBUK);

    // --- GEMM2 (covers zero row N) ---
    k_h<<<(N + 64) / 64, 256, 0, stream>>>(xb, Wgb, affg, dinv, hb, N);

    // --- aggregation + log_softmax ---
    k_agg<<<(N + 3) / 4, 256, 0, stream>>>(hb, csr, offs, pcnt, dinv, bg, out, N);
}